// Round 18
// baseline (547.734 us; speedup 1.0000x reference)
//
#include <hip/hip_runtime.h>
#include <hip/hip_bf16.h>
#include <cstdint>
#include <cstddef>

typedef __hip_bfloat16 bf16;
typedef float f4 __attribute__((ext_vector_type(4)));
typedef float f32x4 __attribute__((ext_vector_type(4)));
typedef short s8v __attribute__((ext_vector_type(8)));
typedef unsigned short u16x4 __attribute__((ext_vector_type(4)));
typedef unsigned short u16x8 __attribute__((ext_vector_type(8)));

#define LN_EPS 1e-5f
#define LOG2E 1.4426950408889634f

#if __has_builtin(__builtin_amdgcn_exp2f)
__device__ __forceinline__ float EXP2(float x) { return __builtin_amdgcn_exp2f(x); }
#else
__device__ __forceinline__ float EXP2(float x) {
  float r; asm("v_exp_f32 %0, %1" : "=v"(r) : "v"(x)); return r;
}
#endif

// async global->LDS 16B per lane: lds dest = base + lane*16 (wave-uniform base)
__device__ __forceinline__ void async_cp16(const void* g, void* lds) {
  __builtin_amdgcn_global_load_lds(
      (const __attribute__((address_space(1))) unsigned int*)g,
      (__attribute__((address_space(3))) unsigned int*)lds, 16, 0, 0);
}

// pack 2 floats -> 2 bf16 in a u32 (round-half-up + byte perm: 3 VALU ops)
__device__ __forceinline__ uint32_t pkbf(float lo, float hi) {
#if __has_builtin(__builtin_amdgcn_perm)
  uint32_t l = __builtin_bit_cast(uint32_t, lo) + 0x8000u;
  uint32_t h = __builtin_bit_cast(uint32_t, hi) + 0x8000u;
  return __builtin_amdgcn_perm(h, l, 0x07060302u);
#else
  uint32_t l = __builtin_bit_cast(uint32_t, lo) + 0x8000u;
  uint32_t h = __builtin_bit_cast(uint32_t, hi) + 0x8000u;
  return (l >> 16) | (h & 0xFFFF0000u);
#endif
}

// ------------------------------------------------------------------
// fused multi-segment cast fp32 -> bf16
// ------------------------------------------------------------------
#define NCAST 16
struct CastArgs {
  const float* in[NCAST];
  bf16* out[NCAST];
  int end4[NCAST];
  int nseg;
};

__global__ __launch_bounds__(256) void cast_multi(CastArgs a, int total4) {
  int i = blockIdx.x * 256 + threadIdx.x;
  if (i >= total4) return;
  int s = 0;
  while (i >= a.end4[s]) ++s;
  int j = i - (s ? a.end4[s - 1] : 0);
  f4 v = ((const f4*)a.in[s])[j];
  u16x4 o;
#pragma unroll
  for (int c = 0; c < 4; ++c) {
    bf16 h = __float2bfloat16(v[c]);
    o[c] = *reinterpret_cast<unsigned short*>(&h);
  }
  ((u16x4*)a.out[s])[j] = o;
}

// ------------------------------------------------------------------
// encoder prologue: memb = bf16(src); qkb = bf16(src + pos)
// ------------------------------------------------------------------
__global__ __launch_bounds__(256) void enc_prolog(
    const float* __restrict__ src, const float* __restrict__ pos,
    bf16* __restrict__ memb, bf16* __restrict__ qkb, int n4) {
  int i = blockIdx.x * 256 + threadIdx.x;
  if (i < n4) {
    f4 s = ((const f4*)src)[i];
    f4 p = ((const f4*)pos)[i];
    u16x4 om, oq;
#pragma unroll
    for (int j = 0; j < 4; ++j) {
      bf16 hm = __float2bfloat16(s[j]);
      bf16 hq = __float2bfloat16(s[j] + p[j]);
      om[j] = *reinterpret_cast<unsigned short*>(&hm);
      oq[j] = *reinterpret_cast<unsigned short*>(&hq);
    }
    ((u16x4*)memb)[i] = om;
    ((u16x4*)qkb)[i] = oq;
  }
}

// pack CA K/V biases: [K0;K1;V0;V1]
__global__ __launch_bounds__(256) void pack_pb(const float* __restrict__ qkvb,
                                               float* __restrict__ pb) {
  int j = threadIdx.x;
  pb[j]       = qkvb[256 + j];
  pb[256 + j] = qkvb[768 + 256 + j];
  pb[512 + j] = qkvb[512 + j];
  pb[768 + j] = qkvb[768 + 512 + j];
}

// ------------------------------------------------------------------
// Decoder layer-0 SA shortcut: tgt==0 -> SA output is the constant row
// y = Wo @ bv + bo; ln1 row = LN(y). One block computes + LNs the row.
// ------------------------------------------------------------------
__global__ __launch_bounds__(256) void sa0_row(
    const float* __restrict__ Wo, const float* __restrict__ bv,
    const float* __restrict__ bo, const float* __restrict__ g,
    const float* __restrict__ b, float* __restrict__ row_out) {
  const int j = threadIdx.x;
  float acc = bo[j];
  for (int k = 0; k < 256; k += 4) {
    f4 w = *(const f4*)(Wo + (size_t)j * 256 + k);
    f4 v = *(const f4*)(bv + k);
    acc += w[0] * v[0] + w[1] * v[1] + w[2] * v[2] + w[3] * v[3];
  }
  float s = acc, s2 = acc * acc;
#pragma unroll
  for (int off = 32; off >= 1; off >>= 1) {
    s += __shfl_down(s, off);
    s2 += __shfl_down(s2, off);
  }
  __shared__ float red[8];
  int wv = j >> 6;
  if ((j & 63) == 0) { red[wv] = s; red[4 + wv] = s2; }
  __syncthreads();
  if (j == 0) {
    float ts = red[0] + red[1] + red[2] + red[3];
    float ts2 = red[4] + red[5] + red[6] + red[7];
    float mu = ts * (1.f / 256.f);
    float var = ts2 * (1.f / 256.f) - mu * mu;
    red[0] = mu;
    red[1] = rsqrtf(var + LN_EPS);
  }
  __syncthreads();
  row_out[j] = (acc - red[0]) * red[1] * g[j] + b[j];
}

// broadcast LN'd row -> tgt (f32), tgtb (bf16), tqkb = bf16(row + qe)
__global__ __launch_bounds__(256) void sa0_bcast(
    const float* __restrict__ row, const float* __restrict__ qe,
    float* __restrict__ tgt, bf16* __restrict__ tgtb, bf16* __restrict__ tqkb) {
  const int r = blockIdx.x, j = threadIdx.x;
  float y = row[j];
  size_t idx = (size_t)r * 256 + j;
  tgt[idx] = y;
  tgtb[idx] = __float2bfloat16(y);
  tqkb[idx] = __float2bfloat16(y + qe[idx]);
}

// ------------------------------------------------------------------
// Fused GEMM + bias + residual + LayerNorm (N = 256 fixed).
// C0[M,256] = A[M,K] @ W[256,K]^T + bias; v = res + C0; y = LN(v)*g + b
// out = y (f32), outb = bf16(y), optional auxb = bf16(y + aux).
// Block: 64 rows x 256 cols; wave w owns rows w*16..w*16+15 (all cols)
// -> each LN row is within one 16-lane group (4 shfl_xor, no LDS).
// Staging: LDS pool rows 0..63 = A-tile, 64..319 = W (col r-64), 64
// k-elems per row, XOR-swizzled like mfma_gemm. grid = M/64.
// ------------------------------------------------------------------
__global__ __launch_bounds__(256) void gemm_ln(
    const bf16* __restrict__ A, const bf16* __restrict__ W,
    const float* __restrict__ bias, const float* __restrict__ res,
    const float* __restrict__ g, const float* __restrict__ b,
    float* __restrict__ out, bf16* __restrict__ outb,
    const float* __restrict__ aux, bf16* __restrict__ auxb,
    int M, int K) {
  __shared__ __attribute__((aligned(16))) unsigned short SH[320 * 64];
  const int tid = threadIdx.x;
  const int lane = tid & 63, wave = tid >> 6;
  const int fr = lane & 15, fo = lane >> 4;
  const int srowi = lane >> 3;
  const int slot = lane & 7;
  const int gcol = (slot ^ srowi) * 8;
  const int bm = blockIdx.x * 64;

  f32x4 acc[16] = {};

  for (int k0 = 0; k0 < K; k0 += 64) {
    __syncthreads();
#pragma unroll
    for (int c = 0; c < 10; ++c) {
      int rbase = c * 32 + wave * 8;
      int row = rbase + srowi;
      const bf16* src = (row < 64)
          ? A + (size_t)(bm + row) * K + k0 + gcol
          : W + (size_t)(row - 64) * K + k0 + gcol;
      async_cp16(src, SH + (size_t)rbase * 64);
    }
    __syncthreads();
#pragma unroll
    for (int ks = 0; ks < 2; ++ks) {
      int ar = wave * 16 + fr;
      s8v a = *(const s8v*)((const char*)SH + ar * 128 +
                            ((ks * 64 + fo * 16) ^ ((ar & 7) << 4)));
#pragma unroll
      for (int ni = 0; ni < 16; ++ni) {
        int wrow = 64 + ni * 16 + fr;
        s8v bf = *(const s8v*)((const char*)SH + wrow * 128 +
                               ((ks * 64 + fo * 16) ^ ((wrow & 7) << 4)));
        acc[ni] = __builtin_amdgcn_mfma_f32_16x16x32_bf16(a, bf, acc[ni], 0, 0, 0);
      }
    }
  }

  // epilogue: bias + residual, per-row LN within 16-lane group
  const int r0 = fo * 4;
  float vv[4][16];
#pragma unroll
  for (int ni = 0; ni < 16; ++ni) {
    int col = ni * 16 + fr;
    float bv = bias[col];
#pragma unroll
    for (int r = 0; r < 4; ++r) {
      int grow = bm + wave * 16 + r0 + r;
      vv[r][ni] = acc[ni][r] + bv + res[(size_t)grow * 256 + col];
    }
  }
  float mu[4], rstd[4];
#pragma unroll
  for (int r = 0; r < 4; ++r) {
    float s = 0.f, s2 = 0.f;
#pragma unroll
    for (int ni = 0; ni < 16; ++ni) { s += vv[r][ni]; s2 += vv[r][ni] * vv[r][ni]; }
#pragma unroll
    for (int off = 1; off <= 8; off <<= 1) {
      s += __shfl_xor(s, off);
      s2 += __shfl_xor(s2, off);
    }
    float m = s * (1.f / 256.f);
    float var = s2 * (1.f / 256.f) - m * m;
    mu[r] = m;
    rstd[r] = rsqrtf(var + LN_EPS);
  }
#pragma unroll
  for (int ni = 0; ni < 16; ++ni) {
    int col = ni * 16 + fr;
    float gg = g[col], bb = b[col];
#pragma unroll
    for (int r = 0; r < 4; ++r) {
      int grow = bm + wave * 16 + r0 + r;
      size_t idx = (size_t)grow * 256 + col;
      float y = (vv[r][ni] - mu[r]) * rstd[r] * gg + bb;
      out[idx] = y;
      outb[idx] = __float2bfloat16(y);
      if (auxb) auxb[idx] = __float2bfloat16(y + aux[idx]);
    }
  }
}

// ------------------------------------------------------------------
// MFMA GEMM: C[M,N] = A[M,K] @ W[N,K]^T (+ bias[N])
// MODE: 0 f32, 2 bf16+relu, 3 bf16 head layout (sec0 scaled by qscale),
//       4 f32 split-K partial (no bias),
//       5 bf16 transposed head layout (V^T) via LDS-transpose epilogue
//       6 merged QKV: blocks y<nyA stage from A, else A2; sections
//         col>>8 < secV -> head layout into Cb (qscale on sec0),
//         else V^T into Cb2 (secOut = sec - secV). TB must be 64.
// ------------------------------------------------------------------
template <int TB, int MODE, int SPLITK>
__global__ __launch_bounds__(256, 2) void mfma_gemm(
    const bf16* __restrict__ A, const bf16* __restrict__ W,
    const float* __restrict__ bias, float* __restrict__ C,
    bf16* __restrict__ Cb, int M, int N, int K, int HL, float qscale,
    const bf16* __restrict__ A2, bf16* __restrict__ Cb2, int nyA, int secV) {
  constexpr int WM = TB / 2, WN = TB / 2;
  constexpr int MR = WM / 16, NR = WN / 16;
  constexpr int NCH = TB / 32;
  __shared__ __attribute__((aligned(16))) unsigned short SH[TB * 128];
  unsigned short (*As)[64] = (unsigned short(*)[64])SH;
  unsigned short (*Ws)[64] = (unsigned short(*)[64])(SH + TB * 64);
  const int tid = threadIdx.x;
  const int lane = tid & 63, wave = tid >> 6;
  const int wr = wave >> 1, wc = wave & 1;
  const int bm = blockIdx.x * TB, bn = blockIdx.y * TB;
  const int fr = lane & 15, fo = lane >> 4;
  const int srowi = lane >> 3;
  const int slot = lane & 7;
  const int gcol = (slot ^ srowi) * 8;

  const bf16* Aeff = (MODE == 6) ? (((int)blockIdx.y < nyA) ? A : A2) : A;

  const int kchunk = K / SPLITK;
  const int kbeg = (SPLITK > 1) ? blockIdx.z * kchunk : 0;

  f32x4 acc[MR][NR] = {};

  for (int k0 = kbeg; k0 < kbeg + kchunk; k0 += 64) {
    __syncthreads();
#pragma unroll
    for (int c = 0; c < NCH; ++c) {
      int rbase = wave * (TB / 4) + c * 8;
      int row = rbase + srowi;
      async_cp16(Aeff + (size_t)(bm + row) * K + k0 + gcol, &As[rbase][0]);
      async_cp16(W + (size_t)(bn + row) * K + k0 + gcol, &Ws[rbase][0]);
    }
    __syncthreads();
#pragma unroll
    for (int ks = 0; ks < 2; ++ks) {
      s8v a[MR], b[NR];
#pragma unroll
      for (int mi = 0; mi < MR; ++mi) {
        int row = wr * WM + mi * 16 + fr;
        a[mi] = *(const s8v*)((const char*)&As[0][0] + row * 128 +
                              ((ks * 64 + fo * 16) ^ ((row & 7) << 4)));
      }
#pragma unroll
      for (int ni = 0; ni < NR; ++ni) {
        int row = wc * WN + ni * 16 + fr;
        b[ni] = *(const s8v*)((const char*)&Ws[0][0] + row * 128 +
                              ((ks * 64 + fo * 16) ^ ((row & 7) << 4)));
      }
#pragma unroll
      for (int mi = 0; mi < MR; ++mi)
#pragma unroll
        for (int ni = 0; ni < NR; ++ni)
          acc[mi][ni] = __builtin_amdgcn_mfma_f32_16x16x32_bf16(
              a[mi], b[ni], acc[mi][ni], 0, 0, 0);
    }
  }

  const int r0 = (lane >> 4) * 4;

  if (MODE == 5 || (MODE == 6 && (bn >> 8) >= secV)) {
    // V^T via LDS transpose (block-uniform section)
    __syncthreads();
    unsigned short (*T)[72] = (unsigned short(*)[72])SH;
#pragma unroll
    for (int mi = 0; mi < MR; ++mi)
#pragma unroll
      for (int ni = 0; ni < NR; ++ni) {
        int colL = wc * WN + ni * 16 + fr;
        float bv = bias[bn + colL];
#pragma unroll
        for (int r = 0; r < 4; ++r) {
          int rowL = wr * WM + mi * 16 + r0 + r;
          bf16 hv = __float2bfloat16(acc[mi][ni][r] + bv);
          T[colL][rowL] = *(unsigned short*)&hv;
        }
      }
    __syncthreads();
    bf16* Cv = (MODE == 6) ? Cb2 : Cb;
    const int secBase = (MODE == 6) ? secV : 0;
    const int lbase = bm >> 3;
#pragma unroll
    for (int jj = 0; jj < 2; ++jj) {
      int cid = tid * 2 + jj;
      int colL = cid >> 3, bb = cid & 7;
      int c = bn + colL;
      int sec = (c >> 8) - secBase, hh = (c >> 5) & 7, d = c & 31;
      u16x8 v;
#pragma unroll
      for (int l = 0; l < 8; ++l) v[l] = T[colL][bb + 8 * l];
      *(u16x8*)(Cv + (size_t)sec * ((size_t)64 * 32 * HL) +
                ((size_t)(bb * 8 + hh) * 32 + d) * HL + lbase) = v;
    }
    return;
  }

  float* Cz = (MODE == 4) ? C + (size_t)blockIdx.z * M * N : C;
#pragma unroll
  for (int mi = 0; mi < MR; ++mi) {
#pragma unroll
    for (int ni = 0; ni < NR; ++ni) {
      int col = bn + wc * WN + ni * 16 + fr;
      float bv = (MODE == 4) ? 0.f : bias[col];
#pragma unroll
      for (int r = 0; r < 4; ++r) {
        int row = bm + wr * WM + mi * 16 + r0 + r;
        float t = acc[mi][ni][r] + bv;
        if (MODE == 2) t = fmaxf(t, 0.f);
        if (MODE == 0) {
          C[(size_t)row * N + col] = t;
        } else if (MODE == 4) {
          Cz[(size_t)row * N + col] = t;
        } else if (MODE == 3 || MODE == 6) {
          int l = row >> 3, bb = row & 7;
          int sec = col >> 8, hh = (col >> 5) & 7, d = col & 31;
          if (sec == 0) t *= qscale;
          Cb[(size_t)sec * ((size_t)64 * HL * 32) +
             ((size_t)(bb * 8 + hh) * HL + l) * 32 + d] = __float2bfloat16(t);
        } else {
          Cb[(size_t)row * N + col] = __float2bfloat16(t);
        }
      }
    }
  }
}

// ------------------------------------------------------------------
// Swapped-operand MFMA flash attention with DUAL independent softmax
// chains per wave + setprio MFMA clusters. Bias (cam_mask) scaled by
// LOG2E at use site (fmaf). (Frozen.)
// ------------------------------------------------------------------
template <int HAS_BIAS, int PARTIAL, int NW>
__global__ __launch_bounds__(NW * 64, 3) void attn_mfma(
    const bf16* __restrict__ Qh, const bf16* __restrict__ Kh,
    const bf16* __restrict__ VhT, const float* __restrict__ bias,
    bf16* __restrict__ O, float* __restrict__ PO, float* __restrict__ PM,
    float* __restrict__ PL, int L, int S, int SC) {
  __shared__ __attribute__((aligned(16))) uint32_t Ps2[NW][2][16][36];
  const int tid = threadIdx.x;
  const int lane = tid & 63, wave = tid >> 6;
  const int fr = lane & 15, fo = lane >> 4;
  const int bh = blockIdx.x;
  const int b = bh >> 3, h = bh & 7;
  const int q0 = blockIdx.y * (NW * 16) + wave * 16;
  const int q = q0 + fr;

  const int cz = PARTIAL ? blockIdx.z : 0;
  const int sb = PARTIAL ? cz * SC : 0;
  const int se = PARTIAL ? min(S, sb + SC) : S;
  const int ng = (se - sb + 63) >> 6;

  s8v qf = {};
  if (q < L) qf = *(const s8v*)(Qh + ((size_t)bh * L + q) * 32 + fo * 8);

  const float* brow = nullptr;
  if (HAS_BIAS) brow = bias + ((size_t)b * L + (q < L ? q : L - 1)) * S;

  const bf16* Kbase = Kh + (size_t)bh * S * 32;
  const bf16* Vbase = VhT + (size_t)bh * 32 * S;

  float mA = -1e30f, lsA = 0.f, mB = -1e30f, lsB = 0.f;
  f32x4 oA[2] = {}, oB[2] = {};

  for (int g = 0; g < ng; g += 2) {
    const int sA = sb + g * 64, sB = sA + 64;

    s8v kA[4], kB[4], vA[2][2], vB[2][2];
#pragma unroll
    for (int kb = 0; kb < 4; ++kb) {
      kA[kb] = *(const s8v*)(Kbase + (size_t)(sA + kb * 16 + fr) * 32 + fo * 8);
      kB[kb] = *(const s8v*)(Kbase + (size_t)(sB + kb * 16 + fr) * 32 + fo * 8);
    }
#pragma unroll
    for (int dh = 0; dh < 2; ++dh)
#pragma unroll
      for (int ks = 0; ks < 2; ++ks) {
        vA[dh][ks] = *(const s8v*)(Vbase + (size_t)(dh * 16 + fr) * S +
                                   sA + ks * 32 + fo * 8);
        vB[dh][ks] = *(const s8v*)(Vbase + (size_t)(dh * 16 + fr) * S +
                                   sB + ks * 32 + fo * 8);
      }
    f4 bA[4], bB[4];
    if (HAS_BIAS) {
#pragma unroll
      for (int kb = 0; kb < 4; ++kb) {
        bA[kb] = *(const f4*)(brow + sA + kb * 16 + 4 * fo);
        bB[kb] = *(const f4*)(brow + sB + kb * 16 + 4 * fo);
      }
    }

    float lgA[16], lgB[16];
    __builtin_amdgcn_s_setprio(1);
#pragma unroll
    for (int kb = 0; kb < 4; ++kb) {
      f32x4 z = {};
      f32x4 sa = __builtin_amdgcn_mfma_f32_16x16x32_bf16(kA[kb], qf, z, 0, 0, 0);
#pragma unroll
      for (int r = 0; r < 4; ++r) lgA[kb * 4 + r] = sa[r];
    }
#pragma unroll
    for (int kb = 0; kb < 4; ++kb) {
      f32x4 z = {};
      f32x4 sa = __builtin_amdgcn_mfma_f32_16x16x32_bf16(kB[kb], qf, z, 0, 0, 0);
#pragma unroll
      for (int r = 0; r < 4; ++r) lgB[kb * 4 + r] = sa[r];
    }
    __builtin_amdgcn_s_setprio(0);
    if (HAS_BIAS) {
#pragma unroll
      for (int i = 0; i < 16; ++i) {
        lgA[i] = fmaf(bA[i >> 2][i & 3], LOG2E, lgA[i]);
        lgB[i] = fmaf(bB[i >> 2][i & 3], LOG2E, lgB[i]);
      }
    }
    if (sB + 64 > se) {
#pragma unroll
      for (int i = 0; i < 16; ++i) {
        int keyA = sA + (i >> 2) * 16 + 4 * fo + (i & 3);
        int keyB = sB + (i >> 2) * 16 + 4 * fo + (i & 3);
        if (keyA >= se) lgA[i] = -1e30f;
        if (keyB >= se) lgB[i] = -1e30f;
      }
    }

    float tA, tB;
    {
      float a0 = fmaxf(fmaxf(lgA[0], lgA[1]), fmaxf(lgA[2], lgA[3]));
      float a1 = fmaxf(fmaxf(lgA[4], lgA[5]), fmaxf(lgA[6], lgA[7]));
      float a2 = fmaxf(fmaxf(lgA[8], lgA[9]), fmaxf(lgA[10], lgA[11]));
      float a3 = fmaxf(fmaxf(lgA[12], lgA[13]), fmaxf(lgA[14], lgA[15]));
      tA = fmaxf(fmaxf(a0, a1), fmaxf(a2, a3));
      float b0 = fmaxf(fmaxf(lgB[0], lgB[1]), fmaxf(lgB[2], lgB[3]));
      float b1 = fmaxf(fmaxf(lgB[4], lgB[5]), fmaxf(lgB[6], lgB[7]));
      float b2 = fmaxf(fmaxf(lgB[8], lgB[9]), fmaxf(lgB[10], lgB[11]));
      float b3 = fmaxf(fmaxf(lgB[12], lgB[13]), fmaxf(lgB[14], lgB[15]));
      tB = fmaxf(fmaxf(b0, b1), fmaxf(b2, b3));
    }
    tA = fmaxf(tA, __shfl_xor(tA, 16));
    tB = fmaxf(tB, __shfl_xor(tB, 16));
    tA = fmaxf(tA, __shfl_xor(tA, 32));
    tB = fmaxf(tB, __shfl_xor(tB, 32));

    float nmA = fmaxf(mA, tA), nmB = fmaxf(mB, tB);
    float rsA = EXP2(mA - nmA), rsB = EXP2(mB - nmB);
    mA = nmA; mB = nmB;

    float psA = 0.f, psB = 0.f;
#pragma unroll
    for (int i = 0; i < 16; ++i) {
      lgA[i] = EXP2(lgA[i] - nmA); psA += lgA[i];
      lgB[i] = EXP2(lgB[i] - nmB); psB += lgB[i];
    }
    lsA = lsA * rsA + psA;
    lsB = lsB * rsB + psB;

#pragma unroll
    for (int kb = 0; kb < 4; ++kb) {
      uint32_t a0 = pkbf(lgA[kb * 4 + 0], lgA[kb * 4 + 1]);
      uint32_t a1 = pkbf(lgA[kb * 4 + 2], lgA[kb * 4 + 3]);
      *(uint64_t*)&Ps2[wave][0][fr][kb * 8 + 2 * fo] =
          (uint64_t)a0 | ((uint64_t)a1 << 32);
      uint32_t b0 = pkbf(lgB[kb * 4 + 0], lgB[kb * 4 + 1]);
      uint32_t b1 = pkbf(lgB[kb * 4 + 2], lgB[kb * 4 + 3]);
      *(uint64_t*)&Ps2[wave][1][fr][kb * 8 + 2 * fo] =
          (uint64_t)b0 | ((uint64_t)b1 << 32);
    }

#pragma unroll
    for (int r = 0; r < 4; ++r) {
      oA[0][r] *= rsA; oA[1][r] *= rsA;
      oB[0][r] *= rsB; oB[1][r] *= rsB;
    }
    s8v pA[2], pB[2];
#pragma unroll
    for (int ks = 0; ks < 2; ++ks) {
      pA[ks] = *(const s8v*)&Ps2[wave][0][fr][ks * 16 + 4 * fo];
      pB[ks] = *(const s8v*)&Ps2[wave][1][fr][ks * 16 + 4 * fo];
    }
    __builtin_amdgcn_s_setprio(1);
#pragma unroll
    for (int dh = 0; dh < 2; ++dh)
#pragma unroll
      for (int ks = 0; ks < 2; ++ks) {
        oA[dh] = __builtin_amdgcn_mfma_f32_16x16x32_bf16(vA[dh][ks], pA[ks], oA[dh], 0, 0, 0);
        oB[dh] = __builtin_amdgcn_mfma_f32_16x16x32_bf16(vB[dh][ks], pB[ks], oB[dh], 0, 0, 0);
      }
    __builtin_amdgcn_s_setprio(0);
  }

  float m = fmaxf(mA, mB);
  float wA = EXP2(mA - m), wB = EXP2(mB - m);
  float lsum = lsA * wA + lsB * wB;
  f32x4 oacc[2];
#pragma unroll
  for (int dh = 0; dh < 2; ++dh)
#pragma unroll
    for (int r = 0; r < 4; ++r)
      oacc[dh][r] = oA[dh][r] * wA + oB[dh][r] * wB;

  lsum += __shfl_xor(lsum, 16);
  lsum += __shfl_xor(lsum, 32);

  if (q < L) {
    if (PARTIAL) {
      size_t pi = ((size_t)cz * 64 + bh) * L + q;
      float* po = PO + pi * 32;
#pragma unroll
      for (int dh = 0; dh < 2; ++dh) {
        f4 t2;
#pragma unroll
        for (int r = 0; r < 4; ++r) t2[r] = oacc[dh][r];
        *(f4*)(po + dh * 16 + 4 * fo) = t2;
      }
      if (fo == 0) { PM[pi] = m; PL[pi] = lsum; }
    } else {
      float inv = 1.f / lsum;
      bf16* op = O + ((size_t)q * 8 + b) * 256 + h * 32;
#pragma unroll
      for (int dh = 0; dh < 2; ++dh) {
        uint32_t w0 = pkbf(oacc[dh][0] * inv, oacc[dh][1] * inv);
        uint32_t w1 = pkbf(oacc[dh][2] * inv, oacc[dh][3] * inv);
        *(uint32_t*)(op + dh * 16 + 4 * fo) = w0;
        *(uint32_t*)(op + dh * 16 + 4 * fo + 2) = w1;
      }
    }
  }
}

// ------------------------------------------------------------------
// combine NC S-chunk partials -> O bf16 (thread per (bh,q,d))
// ------------------------------------------------------------------
__global__ __launch_bounds__(256) void attn_combine(
    const float* __restrict__ PO, const float* __restrict__ PM,
    const float* __restrict__ PL, bf16* __restrict__ O, int L, int NC) {
  int gid = blockIdx.x * 256 + threadIdx.x;
  if (gid >= 64 * L * 32) return;
  int d = gid & 31;
  int rem = gid >> 5;
  int q = rem % L, bh = rem / L;
  int b = bh >> 3, h = bh & 7;
  float M = -1e30f;
  for (int c = 0; c < NC; ++c) M = fmaxf(M, PM[((size_t)c * 64 + bh) * L + q]);
  float lsum = 0.f, o = 0.f;
  for (int c = 0; c < NC; ++c) {
    size_t pi = ((size_t)c * 64 + bh) * L + q;
    float w = EXP2(PM[pi] - M);
    lsum += PL[pi] * w;
    o += PO[pi * 32 + d] * w;
  }
  O[((size_t)q * 8 + b) * 256 + h * 32 + d] = __float2bfloat16(o / lsum);
}

// ------------------------------------------------------------------
// LayerNorm over last dim (256) — final norm only.
// ------------------------------------------------------------------
__global__ __launch_bounds__(256) void ln_kernel(
    const float* __restrict__ x,
    const float* __restrict__ g, const float* __restrict__ b,
    float* __restrict__ out) {
  const int row = blockIdx.x, tid = threadIdx.x;
  size_t idx = (size_t)row * 256 + tid;
  float v = x[idx];
  float s = v, s2 = v * v;
#pragma unroll
  for (int off = 32; off >= 1; off >>= 1) {
    s += __shfl_down(s, off);
    s2 += __shfl_down(s2, off);
  }
  __shared__ float red[8];
  int wv = tid >> 6;
  if ((tid & 63) == 0) { red[wv] = s; red[4 + wv] = s2; }
  __syncthreads();
  if (tid == 0) {
    float ts = red[0] + red[1] + red[2] + red[3];
    float ts2 = red[4] + red[5] + red[6] + red[7];
    float mu = ts * (1.f / 256.f);
    float var = ts2 * (1.f / 256.f) - mu * mu;
    red[0] = mu;
    red[1] = rsqrtf(var + LN_EPS);
  }
  __syncthreads();
  out[idx] = (v - red[0]) * red[1] * g[tid] + b[tid];
}

// ------------------------------------------------------------------
// Host orchestration
// ------------------------------------------------------------------
extern "C" void kernel_launch(void* const* d_in, const int* in_sizes, int n_in,
                              void* d_out, int out_size, void* d_ws, size_t ws_size,
                              hipStream_t stream) {
  const float* src         = (const float*)d_in[0];
  const float* pos         = (const float*)d_in[1];
  const float* query_embed = (const float*)d_in[2];
  const float* cam_mask    = (const float*)d_in[3];
  const float* enc_qkv_w   = (const float*)d_in[4];
  const float* enc_qkv_b   = (const float*)d_in[5];
  const float* enc_out_w   = (const float*)d_in[6];
  const float* enc_out_b   = (const float*)d_in[7];
  const float* enc_ln1_g   = (const float*)d_in[8];
  const float* enc_ln1_b   = (const float*)d_in[9];
  const float* enc_ff1_w   = (const float*)d_in[10];
  const float* enc_ff1_b   = (const float*)d_in[11];
  const float* enc_ff2_w   = (const float*)d_in[12];
  const float* enc_ff2_b   = (const float*)d_in[13];
  const float* enc_ln2_g   = (const float*)d_in[14];
  const float* enc_ln2_b   = (const float*)d_in[15];
  const float* dec_sa_qkv_w= (const float*)d_in[16];
  const float* dec_sa_qkv_b= (const float*)d_in[17];
  const float* dec_sa_out_w= (const float*)d_in[18];
  const float* dec_sa_out_b= (const float*)d_in[19];
  const float* dec_ln1_g   = (const float*)d_in[20];
  const float* dec_ln1_b   = (const float*)d_in[21];
  const float* dec_ca_qkv_w= (const float*)d_in[22];
  const float* dec_ca_qkv_b= (const float*)d_in[23];
  const float* dec_ca_out_w= (const float*)d_in[24];
  const float* dec_ca_out_b= (const float*)d_in[25];
  const float* dec_ln2_g   = (const float*)d_in[26];
  const float* dec_ln2_b   = (const float*)d_in[27];
  const float* dec_ff1_w   = (const float*)d_in[28];
  const float* dec_ff1_b   = (const float*)d_in[29];
  const float* dec_ff2_w   = (const float*)d_in[30];
  const float* dec_ff2_b   = (const float*)d_in[31];
  const float* dec_ln3_g   = (const float*)d_in[32];
  const float* dec_ln3_b   = (const float*)d_in[33];
  const float* dec_norm_g  = (const float*)d_in[34];
  const float* dec_norm_b  = (const float*)d_in[35];

  // ---------------- workspace layout ----------------
  size_t off = 0;
  char* base = (char*)d_ws;
  auto af = [&](size_t n) { float* p = (float*)(base + off); off += n * 4; return p; };
  auto ab = [&](size_t n) { bf16*  p = (bf16*)(base + off);  off += n * 2; return p; };

  float* mem  = af(2097152);
  float* PO   = af(8388608);   // CA attn partials
  float* pm   = af(262144);
  float* pl   = af(262144);
  float* pb   = af(1024);      // packed CA K/V biases
  float* row0 = af(256);       // dec layer-0 SA const row (LN'd)
  float* tgt  = af(163840);
  bf16* memb  = ab(2097152);
  bf16* qkb   = ab(2097152);
  bf16* aob   = ab(2097152);
  bf16* ffb   = ab(16777216);
  bf16* bufQ  = ab(4194304);   // Q section + batched-K section
  bf16* bufK  = ab(4194304);   // CA K, both layers
  bf16* bufV  = ab(4194304);   // CA V^T, both layers (enc V^T uses [0..2M))
  bf16* bufVsa= ab(172032);    // SA V^T per layer (+slack)
  bf16* tgtb  = ab(163840);
  bf16* tqkb  = ab(163840);
  bf16* taob  = ab(163840);
  bf16* qeb   = ab(163840);    // bf16(query_embed)
  bf16* tffb  = ab(1310720);
  bf16* w_enc_qkv = ab(393216);
  bf16* w_enc_out = ab(131072);
  bf16* w_enc_ff1 = ab(1048576);
  bf16* w_enc_ff2 = ab(1048576);
  bf16* w_sa_qkv  = ab(393216);
  bf16* w_sa_out  = ab(131072);
  bf16* w_ca_q    = ab(131072);   // [Q0;Q1]
  bf16* w_ca_kv   = ab(262144);   // [K0;K1;V0;V1]
  bf16* w_ca_out  = ab(131072);
  bf16* w_dec_ff1 = ab(1048576);
  bf16* w_dec_ff2 = ab(1048576);

  const float qscale = 0.17677669529663687f * LOG2E;

  // ---- fused weight + query_embed casts ----
  {
    CastArgs ca;
    const float* ins[NCAST] = {
        enc_qkv_w, enc_out_w, enc_ff1_w, enc_ff2_w,
        dec_sa_qkv_w, dec_sa_out_w,
        dec_ca_qkv_w,            // Q0
        dec_ca_qkv_w + 65536,    // K0
        dec_ca_qkv_w + 131072,   // V0
        dec_ca_qkv_w + 196608,   // Q1
        dec_ca_qkv_w + 262144,   // K1
        dec_ca_qkv_w + 327680,   // V1
        dec_ca_out_w, dec_ff1_w, dec_ff2_w, query_embed};
    bf16* outs[NCAST] = {
        w_enc_qkv, w_enc_out, w_enc_ff1, w_enc_ff2,
        w_sa_qkv, w_sa_out,
        w_ca_q,              // Q0
        w_ca_kv,             // K0
        w_ca_kv + 131072,    // V0
        w_ca_q + 65536,      // Q1
        w_ca_kv + 65536,     // K1
        w_ca_kv + 196608,    // V1
        w_ca_out, w_dec_ff1, w_dec_ff2, qeb};
    int n4s[NCAST] = {98304, 32768, 262144, 262144, 98304, 32768,
                      16384, 16384, 16384, 16384, 16384, 16384,
                      32768, 262144, 262144, 40960};
    int acc = 0;
    for (int s = 0; s < NCAST; ++s) {
      ca.in[s] = ins[s]; ca.out[s] = outs[s];
      acc += n4s[s]; ca.end4[s] = acc;
    }
    ca.nseg = NCAST;
    cast_multi<<<(acc + 255) / 256, 256, 0, stream>>>(ca, acc);
  }
  enc_prolog<<<2048, 256, 0, stream>>>(src, pos, memb, qkb, 524288);
  pack_pb<<<1, 256, 0, stream>>>(dec_ca_qkv_b, pb);

  // GEMM launch helpers
  auto g64_head = [&](const bf16* A, const bf16* W, const float* bias, bf16* Cb,
                      int M, int N, int K, int HL, float qs) {
    mfma_gemm<64, 3, 1><<<dim3(M / 64, N / 64), 256, 0, stream>>>(
        A, W, bias, nullptr, Cb, M, N, K, HL, qs, nullptr, nullptr, 0, 0);
  };
  auto g64_relu = [&](const bf16* A, const bf16* W, const float* bias, bf16* Cb,
                      int M, int N, int K) {
    mfma_gemm<64, 2, 1><<<dim3(M / 64, N / 64), 256, 0, stream>>>(
        A, W, bias, nullptr, Cb, M, N, K, 0, 1.f, nullptr, nullptr, 0, 0);
  };
  auto g128_relu = [&](const bf16* A, const bf16* W, const float* bias, bf16* Cb,
                       int M, int N, int K) {
    mfma_gemm<128, 2, 1><<<dim3(M / 128, N / 128), 256, 0, stream>>>(
        A, W, bias, nullptr, Cb, M, N, K, 0, 1.f, nullptr, nullptr, 0, 0);
  };

  // ---------------- encoder ----------------
  for (int i = 0; i < 2; ++i) {
    const bf16* wq = w_enc_qkv + (size_t)i * 196608;
    const float* qkvb = enc_qkv_b + (size_t)i * 768;
    // merged QKV projection: Q+K head layout from qkb, V^T from memb
    mfma_gemm<64, 6, 1><<<dim3(128, 12), 256, 0, stream>>>(
        qkb, wq, qkvb, nullptr, bufQ, 8192, 768, 256, 1024, qscale,
        memb, bufV, 8, 2);
    attn_mfma<0, 0, 4><<<dim3(64, 16), 256, 0, stream>>>(
        bufQ, bufQ + 2097152, bufV, nullptr, aob, nullptr, nullptr, nullptr,
        1024, 1024, 0);
    // fused out-proj + bias + residual + ln1
    gemm_ln<<<128, 256, 0, stream>>>(
        aob, w_enc_out + (size_t)i * 65536, enc_out_b + i * 256,
        (i == 0) ? src : mem, enc_ln1_g + i * 256, enc_ln1_b + i * 256,
        mem, memb, nullptr, nullptr, 8192, 256);
    g128_relu(memb, w_enc_ff1 + (size_t)i * 524288, enc_ff1_b + i * 2048, ffb,
              8192, 2048, 256);
    // fused FF2 + bias + residual + ln2 (+ qkb = bf16(y + pos))
    gemm_ln<<<128, 256, 0, stream>>>(
        ffb, w_enc_ff2 + (size_t)i * 524288, enc_ff2_b + i * 256,
        mem, enc_ln2_g + i * 256, enc_ln2_b + i * 256,
        mem, memb, pos, qkb, 8192, 2048);
  }

  // ---------------- decoder ----------------
  // Hoisted CA K/V projections (both layers, merged K + V^T, N=1024)
  mfma_gemm<64, 6, 1><<<dim3(128, 16), 256, 0, stream>>>(
      qkb, w_ca_kv, pb, nullptr, bufK, 8192, 1024, 256, 1024, 1.f,
      memb, bufV, 8, 2);

  for (int i = 0; i < 2; ++i) {
    const float* sab = dec_sa_qkv_b + (size_t)i * 768;
    const float* cab = dec_ca_qkv_b + (size_t)i * 768;

    if (i == 0) {
      // tgt == 0 -> SA output is the constant row Wo@bv + bo; ln1 row = LN(it)
      sa0_row<<<1, 256, 0, stream>>>(dec_sa_out_w, dec_sa_qkv_b + 512,
                                     dec_sa_out_b, dec_ln1_g, dec_ln1_b, row0);
      sa0_bcast<<<640, 256, 0, stream>>>(row0, query_embed, tgt, tgtb, tqkb);
    } else {
      const bf16* wsa = w_sa_qkv + (size_t)i * 196608;
      // merged SA QKV: Q+K from tqkb (bf16(tgt+qe)), V^T from tgtb
      mfma_gemm<64, 6, 1><<<dim3(10, 12), 256, 0, stream>>>(
          tqkb, wsa, sab, nullptr, bufQ, 640, 768, 256, 80, qscale,
          tgtb, bufVsa, 8, 2);
      attn_mfma<0, 0, 1><<<dim3(64, 5), 64, 0, stream>>>(
          bufQ, bufQ + 163840, bufVsa, nullptr, taob, nullptr, nullptr, nullptr,
          80, 80, 0);
      // fused SA out-proj + residual + ln1 (+ tqkb = bf16(y + qe))
      gemm_ln<<<10, 256, 0, stream>>>(
          taob, w_sa_out + (size_t)i * 65536, dec_sa_out_b + i * 256,
          tgt, dec_ln1_g + i * 256, dec_ln1_b + i * 256,
          tgt, tgtb, query_embed, tqkb, 640, 256);
    }
    // cross-attention (S split into 4 chunks of 256 + combine)
    g64_head(tqkb, w_ca_q + (size_t)i * 65536, cab, bufQ, 640, 256, 256, 80, qscale);
    attn_mfma<1, 1, 1><<<dim3(64, 5, 4), 64, 0, stream>>>(
        bufQ, bufK + (size_t)i * 2097152, bufV + (size_t)i * 2097152, cam_mask,
        nullptr, PO, pm, pl, 80, 1024, 256);
    attn_combine<<<640, 256, 0, stream>>>(PO, pm, pl, taob, 80, 4);
    // fused CA out-proj + residual + ln2
    gemm_ln<<<10, 256, 0, stream>>>(
        taob, w_ca_out + (size_t)i * 65536, dec_ca_out_b + i * 256,
        tgt, dec_ln2_g + i * 256, dec_ln2_b + i * 256,
        tgt, tgtb, nullptr, nullptr, 640, 256);
    // feed-forward
    g64_relu(tgtb, w_dec_ff1 + (size_t)i * 524288, dec_ff1_b + i * 2048, tffb,
             640, 2048, 256);
    // fused FF2 + residual + ln3 (+ tqkb = bf16(y + qe))
    gemm_ln<<<10, 256, 0, stream>>>(
        tffb, w_dec_ff2 + (size_t)i * 524288, dec_ff2_b + i * 256,
        tgt, dec_ln3_g + i * 256, dec_ln3_b + i * 256,
        tgt, tgtb, query_embed, tqkb, 640, 2048);
  }

  // final norm -> fp32 output
  ln_kernel<<<640, 256, 0, stream>>>(tgt, dec_norm_g, dec_norm_b, (float*)d_out);
}

// Round 19
// 376.651 us; speedup vs baseline: 1.4542x; 1.4542x over previous
//
#include <hip/hip_runtime.h>
#include <hip/hip_bf16.h>
#include <cstdint>
#include <cstddef>

typedef __hip_bfloat16 bf16;
typedef float f4 __attribute__((ext_vector_type(4)));
typedef float f32x4 __attribute__((ext_vector_type(4)));
typedef short s8v __attribute__((ext_vector_type(8)));
typedef unsigned short u16x4 __attribute__((ext_vector_type(4)));
typedef unsigned short u16x8 __attribute__((ext_vector_type(8)));

#define LN_EPS 1e-5f
#define LOG2E 1.4426950408889634f

#if __has_builtin(__builtin_amdgcn_exp2f)
__device__ __forceinline__ float EXP2(float x) { return __builtin_amdgcn_exp2f(x); }
#else
__device__ __forceinline__ float EXP2(float x) {
  float r; asm("v_exp_f32 %0, %1" : "=v"(r) : "v"(x)); return r;
}
#endif

// async global->LDS 16B per lane: lds dest = base + lane*16 (wave-uniform base)
__device__ __forceinline__ void async_cp16(const void* g, void* lds) {
  __builtin_amdgcn_global_load_lds(
      (const __attribute__((address_space(1))) unsigned int*)g,
      (__attribute__((address_space(3))) unsigned int*)lds, 16, 0, 0);
}

// pack 2 floats -> 2 bf16 in a u32 (round-half-up + byte perm: 3 VALU ops)
__device__ __forceinline__ uint32_t pkbf(float lo, float hi) {
#if __has_builtin(__builtin_amdgcn_perm)
  uint32_t l = __builtin_bit_cast(uint32_t, lo) + 0x8000u;
  uint32_t h = __builtin_bit_cast(uint32_t, hi) + 0x8000u;
  return __builtin_amdgcn_perm(h, l, 0x07060302u);
#else
  uint32_t l = __builtin_bit_cast(uint32_t, lo) + 0x8000u;
  uint32_t h = __builtin_bit_cast(uint32_t, hi) + 0x8000u;
  return (l >> 16) | (h & 0xFFFF0000u);
#endif
}

// ------------------------------------------------------------------
// fused multi-segment cast fp32 -> bf16
// ------------------------------------------------------------------
#define NCAST 16
struct CastArgs {
  const float* in[NCAST];
  bf16* out[NCAST];
  int end4[NCAST];
  int nseg;
};

__global__ __launch_bounds__(256) void cast_multi(CastArgs a, int total4) {
  int i = blockIdx.x * 256 + threadIdx.x;
  if (i >= total4) return;
  int s = 0;
  while (i >= a.end4[s]) ++s;
  int j = i - (s ? a.end4[s - 1] : 0);
  f4 v = ((const f4*)a.in[s])[j];
  u16x4 o;
#pragma unroll
  for (int c = 0; c < 4; ++c) {
    bf16 h = __float2bfloat16(v[c]);
    o[c] = *reinterpret_cast<unsigned short*>(&h);
  }
  ((u16x4*)a.out[s])[j] = o;
}

// ------------------------------------------------------------------
// encoder prologue: memb = bf16(src); qkb = bf16(src + pos)
// ------------------------------------------------------------------
__global__ __launch_bounds__(256) void enc_prolog(
    const float* __restrict__ src, const float* __restrict__ pos,
    bf16* __restrict__ memb, bf16* __restrict__ qkb, int n4) {
  int i = blockIdx.x * 256 + threadIdx.x;
  if (i < n4) {
    f4 s = ((const f4*)src)[i];
    f4 p = ((const f4*)pos)[i];
    u16x4 om, oq;
#pragma unroll
    for (int j = 0; j < 4; ++j) {
      bf16 hm = __float2bfloat16(s[j]);
      bf16 hq = __float2bfloat16(s[j] + p[j]);
      om[j] = *reinterpret_cast<unsigned short*>(&hm);
      oq[j] = *reinterpret_cast<unsigned short*>(&hq);
    }
    ((u16x4*)memb)[i] = om;
    ((u16x4*)qkb)[i] = oq;
  }
}

// pack CA K/V biases: [K0;K1;V0;V1]
__global__ __launch_bounds__(256) void pack_pb(const float* __restrict__ qkvb,
                                               float* __restrict__ pb) {
  int j = threadIdx.x;
  pb[j]       = qkvb[256 + j];
  pb[256 + j] = qkvb[768 + 256 + j];
  pb[512 + j] = qkvb[512 + j];
  pb[768 + j] = qkvb[768 + 512 + j];
}

// ------------------------------------------------------------------
// Decoder layer-0 SA shortcut: tgt==0 -> SA output is the constant row
// y = Wo @ bv + bo; ln1 row = LN(y). One block computes + LNs the row.
// ------------------------------------------------------------------
__global__ __launch_bounds__(256) void sa0_row(
    const float* __restrict__ Wo, const float* __restrict__ bv,
    const float* __restrict__ bo, const float* __restrict__ g,
    const float* __restrict__ b, float* __restrict__ row_out) {
  const int j = threadIdx.x;
  float acc = bo[j];
  for (int k = 0; k < 256; k += 4) {
    f4 w = *(const f4*)(Wo + (size_t)j * 256 + k);
    f4 v = *(const f4*)(bv + k);
    acc += w[0] * v[0] + w[1] * v[1] + w[2] * v[2] + w[3] * v[3];
  }
  float s = acc, s2 = acc * acc;
#pragma unroll
  for (int off = 32; off >= 1; off >>= 1) {
    s += __shfl_down(s, off);
    s2 += __shfl_down(s2, off);
  }
  __shared__ float red[8];
  int wv = j >> 6;
  if ((j & 63) == 0) { red[wv] = s; red[4 + wv] = s2; }
  __syncthreads();
  if (j == 0) {
    float ts = red[0] + red[1] + red[2] + red[3];
    float ts2 = red[4] + red[5] + red[6] + red[7];
    float mu = ts * (1.f / 256.f);
    float var = ts2 * (1.f / 256.f) - mu * mu;
    red[0] = mu;
    red[1] = rsqrtf(var + LN_EPS);
  }
  __syncthreads();
  row_out[j] = (acc - red[0]) * red[1] * g[j] + b[j];
}

// broadcast LN'd row -> tgt (f32), tgtb (bf16), tqkb = bf16(row + qe)
__global__ __launch_bounds__(256) void sa0_bcast(
    const float* __restrict__ row, const float* __restrict__ qe,
    float* __restrict__ tgt, bf16* __restrict__ tgtb, bf16* __restrict__ tqkb) {
  const int r = blockIdx.x, j = threadIdx.x;
  float y = row[j];
  size_t idx = (size_t)r * 256 + j;
  tgt[idx] = y;
  tgtb[idx] = __float2bfloat16(y);
  tqkb[idx] = __float2bfloat16(y + qe[idx]);
}

// ------------------------------------------------------------------
// MFMA GEMM: C[M,N] = A[M,K] @ W[N,K]^T (+ bias[N])
// MODE: 0 f32, 2 bf16+relu, 3 bf16 head layout (sec0 scaled by qscale),
//       4 f32 split-K partial (no bias),
//       5 bf16 transposed head layout (V^T) via LDS-transpose epilogue
//       6 merged QKV: blocks y<nyA stage from A, else A2; sections
//         col>>8 < secV -> head layout into Cb (qscale on sec0),
//         else V^T into Cb2 (secOut = sec - secV). TB must be 64.
// ------------------------------------------------------------------
template <int TB, int MODE, int SPLITK>
__global__ __launch_bounds__(256, 2) void mfma_gemm(
    const bf16* __restrict__ A, const bf16* __restrict__ W,
    const float* __restrict__ bias, float* __restrict__ C,
    bf16* __restrict__ Cb, int M, int N, int K, int HL, float qscale,
    const bf16* __restrict__ A2, bf16* __restrict__ Cb2, int nyA, int secV) {
  constexpr int WM = TB / 2, WN = TB / 2;
  constexpr int MR = WM / 16, NR = WN / 16;
  constexpr int NCH = TB / 32;
  __shared__ __attribute__((aligned(16))) unsigned short SH[TB * 128];
  unsigned short (*As)[64] = (unsigned short(*)[64])SH;
  unsigned short (*Ws)[64] = (unsigned short(*)[64])(SH + TB * 64);
  const int tid = threadIdx.x;
  const int lane = tid & 63, wave = tid >> 6;
  const int wr = wave >> 1, wc = wave & 1;
  const int bm = blockIdx.x * TB, bn = blockIdx.y * TB;
  const int fr = lane & 15, fo = lane >> 4;
  const int srowi = lane >> 3;
  const int slot = lane & 7;
  const int gcol = (slot ^ srowi) * 8;

  const bf16* Aeff = (MODE == 6) ? (((int)blockIdx.y < nyA) ? A : A2) : A;

  const int kchunk = K / SPLITK;
  const int kbeg = (SPLITK > 1) ? blockIdx.z * kchunk : 0;

  f32x4 acc[MR][NR] = {};

  for (int k0 = kbeg; k0 < kbeg + kchunk; k0 += 64) {
    __syncthreads();
#pragma unroll
    for (int c = 0; c < NCH; ++c) {
      int rbase = wave * (TB / 4) + c * 8;
      int row = rbase + srowi;
      async_cp16(Aeff + (size_t)(bm + row) * K + k0 + gcol, &As[rbase][0]);
      async_cp16(W + (size_t)(bn + row) * K + k0 + gcol, &Ws[rbase][0]);
    }
    __syncthreads();
#pragma unroll
    for (int ks = 0; ks < 2; ++ks) {
      s8v a[MR], b[NR];
#pragma unroll
      for (int mi = 0; mi < MR; ++mi) {
        int row = wr * WM + mi * 16 + fr;
        a[mi] = *(const s8v*)((const char*)&As[0][0] + row * 128 +
                              ((ks * 64 + fo * 16) ^ ((row & 7) << 4)));
      }
#pragma unroll
      for (int ni = 0; ni < NR; ++ni) {
        int row = wc * WN + ni * 16 + fr;
        b[ni] = *(const s8v*)((const char*)&Ws[0][0] + row * 128 +
                              ((ks * 64 + fo * 16) ^ ((row & 7) << 4)));
      }
#pragma unroll
      for (int mi = 0; mi < MR; ++mi)
#pragma unroll
        for (int ni = 0; ni < NR; ++ni)
          acc[mi][ni] = __builtin_amdgcn_mfma_f32_16x16x32_bf16(
              a[mi], b[ni], acc[mi][ni], 0, 0, 0);
    }
  }

  const int r0 = (lane >> 4) * 4;

  if (MODE == 5 || (MODE == 6 && (bn >> 8) >= secV)) {
    // V^T via LDS transpose (block-uniform section)
    __syncthreads();
    unsigned short (*T)[72] = (unsigned short(*)[72])SH;
#pragma unroll
    for (int mi = 0; mi < MR; ++mi)
#pragma unroll
      for (int ni = 0; ni < NR; ++ni) {
        int colL = wc * WN + ni * 16 + fr;
        float bv = bias[bn + colL];
#pragma unroll
        for (int r = 0; r < 4; ++r) {
          int rowL = wr * WM + mi * 16 + r0 + r;
          bf16 hv = __float2bfloat16(acc[mi][ni][r] + bv);
          T[colL][rowL] = *(unsigned short*)&hv;
        }
      }
    __syncthreads();
    bf16* Cv = (MODE == 6) ? Cb2 : Cb;
    const int secBase = (MODE == 6) ? secV : 0;
    const int lbase = bm >> 3;
#pragma unroll
    for (int jj = 0; jj < 2; ++jj) {
      int cid = tid * 2 + jj;
      int colL = cid >> 3, bb = cid & 7;
      int c = bn + colL;
      int sec = (c >> 8) - secBase, hh = (c >> 5) & 7, d = c & 31;
      u16x8 v;
#pragma unroll
      for (int l = 0; l < 8; ++l) v[l] = T[colL][bb + 8 * l];
      *(u16x8*)(Cv + (size_t)sec * ((size_t)64 * 32 * HL) +
                ((size_t)(bb * 8 + hh) * 32 + d) * HL + lbase) = v;
    }
    return;
  }

  float* Cz = (MODE == 4) ? C + (size_t)blockIdx.z * M * N : C;
#pragma unroll
  for (int mi = 0; mi < MR; ++mi) {
#pragma unroll
    for (int ni = 0; ni < NR; ++ni) {
      int col = bn + wc * WN + ni * 16 + fr;
      float bv = (MODE == 4) ? 0.f : bias[col];
#pragma unroll
      for (int r = 0; r < 4; ++r) {
        int row = bm + wr * WM + mi * 16 + r0 + r;
        float t = acc[mi][ni][r] + bv;
        if (MODE == 2) t = fmaxf(t, 0.f);
        if (MODE == 0) {
          C[(size_t)row * N + col] = t;
        } else if (MODE == 4) {
          Cz[(size_t)row * N + col] = t;
        } else if (MODE == 3 || MODE == 6) {
          int l = row >> 3, bb = row & 7;
          int sec = col >> 8, hh = (col >> 5) & 7, d = col & 31;
          if (sec == 0) t *= qscale;
          Cb[(size_t)sec * ((size_t)64 * HL * 32) +
             ((size_t)(bb * 8 + hh) * HL + l) * 32 + d] = __float2bfloat16(t);
        } else {
          Cb[(size_t)row * N + col] = __float2bfloat16(t);
        }
      }
    }
  }
}

// ------------------------------------------------------------------
// Swapped-operand MFMA flash attention with DUAL independent softmax
// chains per wave + setprio MFMA clusters. Bias (cam_mask) scaled by
// LOG2E at use site (fmaf). (Frozen.)
// ------------------------------------------------------------------
template <int HAS_BIAS, int PARTIAL, int NW>
__global__ __launch_bounds__(NW * 64, 3) void attn_mfma(
    const bf16* __restrict__ Qh, const bf16* __restrict__ Kh,
    const bf16* __restrict__ VhT, const float* __restrict__ bias,
    bf16* __restrict__ O, float* __restrict__ PO, float* __restrict__ PM,
    float* __restrict__ PL, int L, int S, int SC) {
  __shared__ __attribute__((aligned(16))) uint32_t Ps2[NW][2][16][36];
  const int tid = threadIdx.x;
  const int lane = tid & 63, wave = tid >> 6;
  const int fr = lane & 15, fo = lane >> 4;
  const int bh = blockIdx.x;
  const int b = bh >> 3, h = bh & 7;
  const int q0 = blockIdx.y * (NW * 16) + wave * 16;
  const int q = q0 + fr;

  const int cz = PARTIAL ? blockIdx.z : 0;
  const int sb = PARTIAL ? cz * SC : 0;
  const int se = PARTIAL ? min(S, sb + SC) : S;
  const int ng = (se - sb + 63) >> 6;

  s8v qf = {};
  if (q < L) qf = *(const s8v*)(Qh + ((size_t)bh * L + q) * 32 + fo * 8);

  const float* brow = nullptr;
  if (HAS_BIAS) brow = bias + ((size_t)b * L + (q < L ? q : L - 1)) * S;

  const bf16* Kbase = Kh + (size_t)bh * S * 32;
  const bf16* Vbase = VhT + (size_t)bh * 32 * S;

  float mA = -1e30f, lsA = 0.f, mB = -1e30f, lsB = 0.f;
  f32x4 oA[2] = {}, oB[2] = {};

  for (int g = 0; g < ng; g += 2) {
    const int sA = sb + g * 64, sB = sA + 64;

    s8v kA[4], kB[4], vA[2][2], vB[2][2];
#pragma unroll
    for (int kb = 0; kb < 4; ++kb) {
      kA[kb] = *(const s8v*)(Kbase + (size_t)(sA + kb * 16 + fr) * 32 + fo * 8);
      kB[kb] = *(const s8v*)(Kbase + (size_t)(sB + kb * 16 + fr) * 32 + fo * 8);
    }
#pragma unroll
    for (int dh = 0; dh < 2; ++dh)
#pragma unroll
      for (int ks = 0; ks < 2; ++ks) {
        vA[dh][ks] = *(const s8v*)(Vbase + (size_t)(dh * 16 + fr) * S +
                                   sA + ks * 32 + fo * 8);
        vB[dh][ks] = *(const s8v*)(Vbase + (size_t)(dh * 16 + fr) * S +
                                   sB + ks * 32 + fo * 8);
      }
    f4 bA[4], bB[4];
    if (HAS_BIAS) {
#pragma unroll
      for (int kb = 0; kb < 4; ++kb) {
        bA[kb] = *(const f4*)(brow + sA + kb * 16 + 4 * fo);
        bB[kb] = *(const f4*)(brow + sB + kb * 16 + 4 * fo);
      }
    }

    float lgA[16], lgB[16];
    __builtin_amdgcn_s_setprio(1);
#pragma unroll
    for (int kb = 0; kb < 4; ++kb) {
      f32x4 z = {};
      f32x4 sa = __builtin_amdgcn_mfma_f32_16x16x32_bf16(kA[kb], qf, z, 0, 0, 0);
#pragma unroll
      for (int r = 0; r < 4; ++r) lgA[kb * 4 + r] = sa[r];
    }
#pragma unroll
    for (int kb = 0; kb < 4; ++kb) {
      f32x4 z = {};
      f32x4 sa = __builtin_amdgcn_mfma_f32_16x16x32_bf16(kB[kb], qf, z, 0, 0, 0);
#pragma unroll
      for (int r = 0; r < 4; ++r) lgB[kb * 4 + r] = sa[r];
    }
    __builtin_amdgcn_s_setprio(0);
    if (HAS_BIAS) {
#pragma unroll
      for (int i = 0; i < 16; ++i) {
        lgA[i] = fmaf(bA[i >> 2][i & 3], LOG2E, lgA[i]);
        lgB[i] = fmaf(bB[i >> 2][i & 3], LOG2E, lgB[i]);
      }
    }
    if (sB + 64 > se) {
#pragma unroll
      for (int i = 0; i < 16; ++i) {
        int keyA = sA + (i >> 2) * 16 + 4 * fo + (i & 3);
        int keyB = sB + (i >> 2) * 16 + 4 * fo + (i & 3);
        if (keyA >= se) lgA[i] = -1e30f;
        if (keyB >= se) lgB[i] = -1e30f;
      }
    }

    float tA, tB;
    {
      float a0 = fmaxf(fmaxf(lgA[0], lgA[1]), fmaxf(lgA[2], lgA[3]));
      float a1 = fmaxf(fmaxf(lgA[4], lgA[5]), fmaxf(lgA[6], lgA[7]));
      float a2 = fmaxf(fmaxf(lgA[8], lgA[9]), fmaxf(lgA[10], lgA[11]));
      float a3 = fmaxf(fmaxf(lgA[12], lgA[13]), fmaxf(lgA[14], lgA[15]));
      tA = fmaxf(fmaxf(a0, a1), fmaxf(a2, a3));
      float b0 = fmaxf(fmaxf(lgB[0], lgB[1]), fmaxf(lgB[2], lgB[3]));
      float b1 = fmaxf(fmaxf(lgB[4], lgB[5]), fmaxf(lgB[6], lgB[7]));
      float b2 = fmaxf(fmaxf(lgB[8], lgB[9]), fmaxf(lgB[10], lgB[11]));
      float b3 = fmaxf(fmaxf(lgB[12], lgB[13]), fmaxf(lgB[14], lgB[15]));
      tB = fmaxf(fmaxf(b0, b1), fmaxf(b2, b3));
    }
    tA = fmaxf(tA, __shfl_xor(tA, 16));
    tB = fmaxf(tB, __shfl_xor(tB, 16));
    tA = fmaxf(tA, __shfl_xor(tA, 32));
    tB = fmaxf(tB, __shfl_xor(tB, 32));

    float nmA = fmaxf(mA, tA), nmB = fmaxf(mB, tB);
    float rsA = EXP2(mA - nmA), rsB = EXP2(mB - nmB);
    mA = nmA; mB = nmB;

    float psA = 0.f, psB = 0.f;
#pragma unroll
    for (int i = 0; i < 16; ++i) {
      lgA[i] = EXP2(lgA[i] - nmA); psA += lgA[i];
      lgB[i] = EXP2(lgB[i] - nmB); psB += lgB[i];
    }
    lsA = lsA * rsA + psA;
    lsB = lsB * rsB + psB;

#pragma unroll
    for (int kb = 0; kb < 4; ++kb) {
      uint32_t a0 = pkbf(lgA[kb * 4 + 0], lgA[kb * 4 + 1]);
      uint32_t a1 = pkbf(lgA[kb * 4 + 2], lgA[kb * 4 + 3]);
      *(uint64_t*)&Ps2[wave][0][fr][kb * 8 + 2 * fo] =
          (uint64_t)a0 | ((uint64_t)a1 << 32);
      uint32_t b0 = pkbf(lgB[kb * 4 + 0], lgB[kb * 4 + 1]);
      uint32_t b1 = pkbf(lgB[kb * 4 + 2], lgB[kb * 4 + 3]);
      *(uint64_t*)&Ps2[wave][1][fr][kb * 8 + 2 * fo] =
          (uint64_t)b0 | ((uint64_t)b1 << 32);
    }

#pragma unroll
    for (int r = 0; r < 4; ++r) {
      oA[0][r] *= rsA; oA[1][r] *= rsA;
      oB[0][r] *= rsB; oB[1][r] *= rsB;
    }
    s8v pA[2], pB[2];
#pragma unroll
    for (int ks = 0; ks < 2; ++ks) {
      pA[ks] = *(const s8v*)&Ps2[wave][0][fr][ks * 16 + 4 * fo];
      pB[ks] = *(const s8v*)&Ps2[wave][1][fr][ks * 16 + 4 * fo];
    }
    __builtin_amdgcn_s_setprio(1);
#pragma unroll
    for (int dh = 0; dh < 2; ++dh)
#pragma unroll
      for (int ks = 0; ks < 2; ++ks) {
        oA[dh] = __builtin_amdgcn_mfma_f32_16x16x32_bf16(vA[dh][ks], pA[ks], oA[dh], 0, 0, 0);
        oB[dh] = __builtin_amdgcn_mfma_f32_16x16x32_bf16(vB[dh][ks], pB[ks], oB[dh], 0, 0, 0);
      }
    __builtin_amdgcn_s_setprio(0);
  }

  float m = fmaxf(mA, mB);
  float wA = EXP2(mA - m), wB = EXP2(mB - m);
  float lsum = lsA * wA + lsB * wB;
  f32x4 oacc[2];
#pragma unroll
  for (int dh = 0; dh < 2; ++dh)
#pragma unroll
    for (int r = 0; r < 4; ++r)
      oacc[dh][r] = oA[dh][r] * wA + oB[dh][r] * wB;

  lsum += __shfl_xor(lsum, 16);
  lsum += __shfl_xor(lsum, 32);

  if (q < L) {
    if (PARTIAL) {
      size_t pi = ((size_t)cz * 64 + bh) * L + q;
      float* po = PO + pi * 32;
#pragma unroll
      for (int dh = 0; dh < 2; ++dh) {
        f4 t2;
#pragma unroll
        for (int r = 0; r < 4; ++r) t2[r] = oacc[dh][r];
        *(f4*)(po + dh * 16 + 4 * fo) = t2;
      }
      if (fo == 0) { PM[pi] = m; PL[pi] = lsum; }
    } else {
      float inv = 1.f / lsum;
      bf16* op = O + ((size_t)q * 8 + b) * 256 + h * 32;
#pragma unroll
      for (int dh = 0; dh < 2; ++dh) {
        uint32_t w0 = pkbf(oacc[dh][0] * inv, oacc[dh][1] * inv);
        uint32_t w1 = pkbf(oacc[dh][2] * inv, oacc[dh][3] * inv);
        *(uint32_t*)(op + dh * 16 + 4 * fo) = w0;
        *(uint32_t*)(op + dh * 16 + 4 * fo + 2) = w1;
      }
    }
  }
}

// ------------------------------------------------------------------
// combine NC S-chunk partials -> O bf16 (thread per (bh,q,d))
// ------------------------------------------------------------------
__global__ __launch_bounds__(256) void attn_combine(
    const float* __restrict__ PO, const float* __restrict__ PM,
    const float* __restrict__ PL, bf16* __restrict__ O, int L, int NC) {
  int gid = blockIdx.x * 256 + threadIdx.x;
  if (gid >= 64 * L * 32) return;
  int d = gid & 31;
  int rem = gid >> 5;
  int q = rem % L, bh = rem / L;
  int b = bh >> 3, h = bh & 7;
  float M = -1e30f;
  for (int c = 0; c < NC; ++c) M = fmaxf(M, PM[((size_t)c * 64 + bh) * L + q]);
  float lsum = 0.f, o = 0.f;
  for (int c = 0; c < NC; ++c) {
    size_t pi = ((size_t)c * 64 + bh) * L + q;
    float w = EXP2(PM[pi] - M);
    lsum += PL[pi] * w;
    o += PO[pi * 32 + d] * w;
  }
  O[((size_t)q * 8 + b) * 256 + h * 32 + d] = __float2bfloat16(o / lsum);
}

// ------------------------------------------------------------------
// LayerNorm over last dim (256): v = x (+res) (+Σ parts) (+gbias);
// out = LN(v)*g + b ; dual output; optional fused add auxb = bf16(y+aux)
// ------------------------------------------------------------------
__global__ __launch_bounds__(256) void ln_kernel(
    const float* __restrict__ x, const float* __restrict__ res,
    const float* __restrict__ parts, int nparts, int pstride,
    const float* __restrict__ gbias,
    const float* __restrict__ g, const float* __restrict__ b,
    float* __restrict__ out, bf16* __restrict__ outb,
    const float* __restrict__ aux, bf16* __restrict__ auxb) {
  const int row = blockIdx.x, tid = threadIdx.x;
  size_t idx = (size_t)row * 256 + tid;
  float v = x[idx];
  if (res) v += res[idx];
  if (parts) {
    for (int z = 0; z < nparts; ++z) v += parts[(size_t)z * pstride + idx];
  }
  if (gbias) v += gbias[tid];
  float s = v, s2 = v * v;
#pragma unroll
  for (int off = 32; off >= 1; off >>= 1) {
    s += __shfl_down(s, off);
    s2 += __shfl_down(s2, off);
  }
  __shared__ float red[8];
  int wv = tid >> 6;
  if ((tid & 63) == 0) { red[wv] = s; red[4 + wv] = s2; }
  __syncthreads();
  if (tid == 0) {
    float ts = red[0] + red[1] + red[2] + red[3];
    float ts2 = red[4] + red[5] + red[6] + red[7];
    float mu = ts * (1.f / 256.f);
    float var = ts2 * (1.f / 256.f) - mu * mu;
    red[0] = mu;
    red[1] = rsqrtf(var + LN_EPS);
  }
  __syncthreads();
  float y = (v - red[0]) * red[1] * g[tid] + b[tid];
  if (out) out[idx] = y;
  if (outb) outb[idx] = __float2bfloat16(y);
  if (auxb) auxb[idx] = __float2bfloat16(y + aux[idx]);
}

// ------------------------------------------------------------------
// Host orchestration
// ------------------------------------------------------------------
extern "C" void kernel_launch(void* const* d_in, const int* in_sizes, int n_in,
                              void* d_out, int out_size, void* d_ws, size_t ws_size,
                              hipStream_t stream) {
  const float* src         = (const float*)d_in[0];
  const float* pos         = (const float*)d_in[1];
  const float* query_embed = (const float*)d_in[2];
  const float* cam_mask    = (const float*)d_in[3];
  const float* enc_qkv_w   = (const float*)d_in[4];
  const float* enc_qkv_b   = (const float*)d_in[5];
  const float* enc_out_w   = (const float*)d_in[6];
  const float* enc_out_b   = (const float*)d_in[7];
  const float* enc_ln1_g   = (const float*)d_in[8];
  const float* enc_ln1_b   = (const float*)d_in[9];
  const float* enc_ff1_w   = (const float*)d_in[10];
  const float* enc_ff1_b   = (const float*)d_in[11];
  const float* enc_ff2_w   = (const float*)d_in[12];
  const float* enc_ff2_b   = (const float*)d_in[13];
  const float* enc_ln2_g   = (const float*)d_in[14];
  const float* enc_ln2_b   = (const float*)d_in[15];
  const float* dec_sa_qkv_w= (const float*)d_in[16];
  const float* dec_sa_qkv_b= (const float*)d_in[17];
  const float* dec_sa_out_w= (const float*)d_in[18];
  const float* dec_sa_out_b= (const float*)d_in[19];
  const float* dec_ln1_g   = (const float*)d_in[20];
  const float* dec_ln1_b   = (const float*)d_in[21];
  const float* dec_ca_qkv_w= (const float*)d_in[22];
  const float* dec_ca_qkv_b= (const float*)d_in[23];
  const float* dec_ca_out_w= (const float*)d_in[24];
  const float* dec_ca_out_b= (const float*)d_in[25];
  const float* dec_ln2_g   = (const float*)d_in[26];
  const float* dec_ln2_b   = (const float*)d_in[27];
  const float* dec_ff1_w   = (const float*)d_in[28];
  const float* dec_ff1_b   = (const float*)d_in[29];
  const float* dec_ff2_w   = (const float*)d_in[30];
  const float* dec_ff2_b   = (const float*)d_in[31];
  const float* dec_ln3_g   = (const float*)d_in[32];
  const float* dec_ln3_b   = (const float*)d_in[33];
  const float* dec_norm_g  = (const float*)d_in[34];
  const float* dec_norm_b  = (const float*)d_in[35];

  // ---------------- workspace layout ----------------
  size_t off = 0;
  char* base = (char*)d_ws;
  auto af = [&](size_t n) { float* p = (float*)(base + off); off += n * 4; return p; };
  auto ab = [&](size_t n) { bf16*  p = (bf16*)(base + off);  off += n * 2; return p; };

  float* mem  = af(2097152);
  float* PO   = af(8388608);   // split-K / attn partials
  float* pm   = af(262144);
  float* pl   = af(262144);
  float* pb   = af(1024);      // packed CA K/V biases
  float* row0 = af(256);       // dec layer-0 SA const row (LN'd)
  float* tgt  = af(163840);
  bf16* memb  = ab(2097152);
  bf16* qkb   = ab(2097152);
  bf16* aob   = ab(2097152);
  bf16* ffb   = ab(16777216);
  bf16* bufQ  = ab(4194304);   // Q section + batched-K section
  bf16* bufK  = ab(4194304);   // CA K, both layers
  bf16* bufV  = ab(4194304);   // CA V^T, both layers (enc V^T uses [0..2M))
  bf16* bufVsa= ab(172032);    // SA V^T per layer (+slack)
  bf16* tgtb  = ab(163840);
  bf16* tqkb  = ab(163840);
  bf16* taob  = ab(163840);
  bf16* qeb   = ab(163840);    // bf16(query_embed)
  bf16* tffb  = ab(1310720);
  bf16* w_enc_qkv = ab(393216);
  bf16* w_enc_out = ab(131072);
  bf16* w_enc_ff1 = ab(1048576);
  bf16* w_enc_ff2 = ab(1048576);
  bf16* w_sa_qkv  = ab(393216);
  bf16* w_sa_out  = ab(131072);
  bf16* w_ca_q    = ab(131072);   // [Q0;Q1]
  bf16* w_ca_kv   = ab(262144);   // [K0;K1;V0;V1]
  bf16* w_ca_out  = ab(131072);
  bf16* w_dec_ff1 = ab(1048576);
  bf16* w_dec_ff2 = ab(1048576);

  const float qscale = 0.17677669529663687f * LOG2E;

  // ---- fused weight + query_embed casts ----
  {
    CastArgs ca;
    const float* ins[NCAST] = {
        enc_qkv_w, enc_out_w, enc_ff1_w, enc_ff2_w,
        dec_sa_qkv_w, dec_sa_out_w,
        dec_ca_qkv_w,            // Q0
        dec_ca_qkv_w + 65536,    // K0
        dec_ca_qkv_w + 131072,   // V0
        dec_ca_qkv_w + 196608,   // Q1
        dec_ca_qkv_w + 262144,   // K1
        dec_ca_qkv_w + 327680,   // V1
        dec_ca_out_w, dec_ff1_w, dec_ff2_w, query_embed};
    bf16* outs[NCAST] = {
        w_enc_qkv, w_enc_out, w_enc_ff1, w_enc_ff2,
        w_sa_qkv, w_sa_out,
        w_ca_q,              // Q0
        w_ca_kv,             // K0
        w_ca_kv + 131072,    // V0
        w_ca_q + 65536,      // Q1
        w_ca_kv + 65536,     // K1
        w_ca_kv + 196608,    // V1
        w_ca_out, w_dec_ff1, w_dec_ff2, qeb};
    int n4s[NCAST] = {98304, 32768, 262144, 262144, 98304, 32768,
                      16384, 16384, 16384, 16384, 16384, 16384,
                      32768, 262144, 262144, 40960};
    int acc = 0;
    for (int s = 0; s < NCAST; ++s) {
      ca.in[s] = ins[s]; ca.out[s] = outs[s];
      acc += n4s[s]; ca.end4[s] = acc;
    }
    ca.nseg = NCAST;
    cast_multi<<<(acc + 255) / 256, 256, 0, stream>>>(ca, acc);
  }
  enc_prolog<<<2048, 256, 0, stream>>>(src, pos, memb, qkb, 524288);
  pack_pb<<<1, 256, 0, stream>>>(dec_ca_qkv_b, pb);

  // GEMM launch helpers
  auto g64_head = [&](const bf16* A, const bf16* W, const float* bias, bf16* Cb,
                      int M, int N, int K, int HL, float qs) {
    mfma_gemm<64, 3, 1><<<dim3(M / 64, N / 64), 256, 0, stream>>>(
        A, W, bias, nullptr, Cb, M, N, K, HL, qs, nullptr, nullptr, 0, 0);
  };
  auto g64_relu = [&](const bf16* A, const bf16* W, const float* bias, bf16* Cb,
                      int M, int N, int K) {
    mfma_gemm<64, 2, 1><<<dim3(M / 64, N / 64), 256, 0, stream>>>(
        A, W, bias, nullptr, Cb, M, N, K, 0, 1.f, nullptr, nullptr, 0, 0);
  };
  auto g128_relu = [&](const bf16* A, const bf16* W, const float* bias, bf16* Cb,
                       int M, int N, int K) {
    mfma_gemm<128, 2, 1><<<dim3(M / 128, N / 128), 256, 0, stream>>>(
        A, W, bias, nullptr, Cb, M, N, K, 0, 1.f, nullptr, nullptr, 0, 0);
  };

  // ---------------- encoder ----------------
  for (int i = 0; i < 2; ++i) {
    const bf16* wq = w_enc_qkv + (size_t)i * 196608;
    const float* qkvb = enc_qkv_b + (size_t)i * 768;
    // merged QKV projection: Q+K head layout from qkb, V^T from memb
    mfma_gemm<64, 6, 1><<<dim3(128, 12), 256, 0, stream>>>(
        qkb, wq, qkvb, nullptr, bufQ, 8192, 768, 256, 1024, qscale,
        memb, bufV, 8, 2);
    attn_mfma<0, 0, 4><<<dim3(64, 16), 256, 0, stream>>>(
        bufQ, bufQ + 2097152, bufV, nullptr, aob, nullptr, nullptr, nullptr,
        1024, 1024, 0);
    // out-proj: split-K=2 -> f32 partials; bias + residual + LN fused below
    mfma_gemm<64, 4, 2><<<dim3(128, 4, 2), 256, 0, stream>>>(
        aob, w_enc_out + (size_t)i * 65536, nullptr, PO, nullptr,
        8192, 256, 256, 0, 1.f, nullptr, nullptr, 0, 0);
    ln_kernel<<<8192, 256, 0, stream>>>((i == 0) ? src : mem, nullptr, PO, 2, 2097152,
                                        enc_out_b + i * 256,
                                        enc_ln1_g + i * 256, enc_ln1_b + i * 256,
                                        mem, memb, nullptr, nullptr);
    g128_relu(memb, w_enc_ff1 + (size_t)i * 524288, enc_ff1_b + i * 2048, ffb,
              8192, 2048, 256);
    mfma_gemm<64, 4, 2><<<dim3(128, 4, 2), 256, 0, stream>>>(
        ffb, w_enc_ff2 + (size_t)i * 524288, nullptr, PO, nullptr,
        8192, 256, 2048, 0, 1.f, nullptr, nullptr, 0, 0);
    // ln2: also emits qkb = bf16(y + pos) (next layer's QK input / CA key input)
    ln_kernel<<<8192, 256, 0, stream>>>(mem, nullptr, PO, 2, 2097152,
                                        enc_ff2_b + i * 256,
                                        enc_ln2_g + i * 256, enc_ln2_b + i * 256,
                                        mem, memb, pos, qkb);
  }

  // ---------------- decoder ----------------
  // Hoisted CA K/V projections (both layers, merged K + V^T, N=1024)
  mfma_gemm<64, 6, 1><<<dim3(128, 16), 256, 0, stream>>>(
      qkb, w_ca_kv, pb, nullptr, bufK, 8192, 1024, 256, 1024, 1.f,
      memb, bufV, 8, 2);

  for (int i = 0; i < 2; ++i) {
    const float* sab = dec_sa_qkv_b + (size_t)i * 768;
    const float* cab = dec_ca_qkv_b + (size_t)i * 768;

    if (i == 0) {
      // tgt == 0 -> SA output is the constant row Wo@bv + bo; ln1 row = LN(it)
      sa0_row<<<1, 256, 0, stream>>>(dec_sa_out_w, dec_sa_qkv_b + 512,
                                     dec_sa_out_b, dec_ln1_g, dec_ln1_b, row0);
      sa0_bcast<<<640, 256, 0, stream>>>(row0, query_embed, tgt, tgtb, tqkb);
    } else {
      const bf16* wsa = w_sa_qkv + (size_t)i * 196608;
      // merged SA QKV: Q+K from tqkb (bf16(tgt+qe)), V^T from tgtb
      mfma_gemm<64, 6, 1><<<dim3(10, 12), 256, 0, stream>>>(
          tqkb, wsa, sab, nullptr, bufQ, 640, 768, 256, 80, qscale,
          tgtb, bufVsa, 8, 2);
      attn_mfma<0, 0, 1><<<dim3(64, 5), 64, 0, stream>>>(
          bufQ, bufQ + 163840, bufVsa, nullptr, taob, nullptr, nullptr, nullptr,
          80, 80, 0);
      mfma_gemm<64, 4, 4><<<dim3(10, 4, 4), 256, 0, stream>>>(
          taob, w_sa_out + (size_t)i * 65536, nullptr, PO, nullptr,
          640, 256, 256, 0, 1.f, nullptr, nullptr, 0, 0);
      // ln1: also emits tqkb = bf16(y + query_embed) (CA Q input)
      ln_kernel<<<640, 256, 0, stream>>>(tgt, nullptr, PO, 4, 163840,
                                         dec_sa_out_b + i * 256,
                                         dec_ln1_g + i * 256, dec_ln1_b + i * 256,
                                         tgt, tgtb, query_embed, tqkb);
    }
    // cross-attention (S split into 4 chunks of 256 + combine)
    g64_head(tqkb, w_ca_q + (size_t)i * 65536, cab, bufQ, 640, 256, 256, 80, qscale);
    attn_mfma<1, 1, 1><<<dim3(64, 5, 4), 64, 0, stream>>>(
        bufQ, bufK + (size_t)i * 2097152, bufV + (size_t)i * 2097152, cam_mask,
        nullptr, PO + 4194304, pm, pl, 80, 1024, 256);
    attn_combine<<<640, 256, 0, stream>>>(PO + 4194304, pm, pl, taob, 80, 4);
    mfma_gemm<64, 4, 4><<<dim3(10, 4, 4), 256, 0, stream>>>(
        taob, w_ca_out + (size_t)i * 65536, nullptr, PO, nullptr,
        640, 256, 256, 0, 1.f, nullptr, nullptr, 0, 0);
    ln_kernel<<<640, 256, 0, stream>>>(tgt, nullptr, PO, 4, 163840,
                                       dec_ca_out_b + i * 256,
                                       dec_ln2_g + i * 256, dec_ln2_b + i * 256,
                                       tgt, tgtb, nullptr, nullptr);
    // feed-forward
    g64_relu(tgtb, w_dec_ff1 + (size_t)i * 524288, dec_ff1_b + i * 2048, tffb,
             640, 2048, 256);
    mfma_gemm<64, 4, 4><<<dim3(10, 4, 4), 256, 0, stream>>>(
        tffb, w_dec_ff2 + (size_t)i * 524288, nullptr, PO, nullptr,
        640, 256, 2048, 0, 1.f, nullptr, nullptr, 0, 0);
    // ln3: also emits tqkb = bf16(y + query_embed) (next layer's SA input)
    ln_kernel<<<640, 256, 0, stream>>>(tgt, nullptr, PO, 4, 163840,
                                       dec_ff2_b + i * 256,
                                       dec_ln3_g + i * 256, dec_ln3_b + i * 256,
                                       tgt, tgtb, query_embed, tqkb);
  }

  // final norm -> fp32 output
  ln_kernel<<<640, 256, 0, stream>>>(tgt, nullptr, nullptr, 0, 0, nullptr,
                                     dec_norm_g, dec_norm_b,
                                     (float*)d_out, nullptr, nullptr, nullptr);
}